// Round 9
// baseline (583.195 us; speedup 1.0000x reference)
//
#include <hip/hip_runtime.h>
#include <hip/hip_bf16.h>

#define NBMAX 256   // coarse buckets per direction
#define TILE  4096  // edges per staged-scatter tile
#define KPT   16    // TILE / 256
#define BINSMAX 512 // max fine bins per bucket

// seg(student) in [0,8): near-uniform 8-way split via magic multiply
__device__ __forceinline__ int seg8(unsigned r, unsigned mult8) {
    return (int)__umulhi(r, mult8);
}

// ---------------- A1: coarse histogram, all 4 dirs (LDS-privatized) ---------
__global__ __launch_bounds__(256) void hist_all(
        const int* __restrict__ k0, const int* __restrict__ k1,
        const int* __restrict__ k2, const int* __restrict__ k3,
        int* __restrict__ gcnt4, int nnz, int rsh_s, int rsh_p) {
    __shared__ int h[NBMAX];
    int dir = blockIdx.x & 3;
    const int* key = (dir == 0) ? k0 : (dir == 1) ? k1 : (dir == 2) ? k2 : k3;
    int rsh = (dir & 1) ? rsh_p : rsh_s;
    h[threadIdx.x] = 0;
    __syncthreads();
    int ch = blockIdx.x >> 2, nch = gridDim.x >> 2;
    int nnz4 = nnz >> 2;
    for (int i = ch * 256 + threadIdx.x; i < nnz4; i += nch * 256) {
        int4 k4 = ((const int4*)key)[i];
        atomicAdd(&h[k4.x >> rsh], 1);
        atomicAdd(&h[k4.y >> rsh], 1);
        atomicAdd(&h[k4.z >> rsh], 1);
        atomicAdd(&h[k4.w >> rsh], 1);
    }
    if (ch == 0) {
        for (int i = (nnz4 << 2) + threadIdx.x; i < nnz; i += 256)
            atomicAdd(&h[key[i] >> rsh], 1);
    }
    __syncthreads();
    int v = h[threadIdx.x];
    if (v) atomicAdd(&gcnt4[dir * NBMAX + threadIdx.x], v);
}

// ---------------- A2: bucket offsets for all 4 dirs (4 blocks) --------------
__global__ __launch_bounds__(256) void scan_all(
        const int* __restrict__ gcnt4, int* __restrict__ boffs4,
        int* __restrict__ bcur4, int nb_s, int nb_p, int nnz,
        int* __restrict__ offsE, int* __restrict__ offsO, int NS, int NP8) {
    __shared__ int tmp[NBMAX];
    int dir = blockIdx.x, tid = threadIdx.x;
    int nb = (dir & 1) ? nb_p : nb_s;
    int v = (tid < nb) ? gcnt4[dir * NBMAX + tid] : 0;
    tmp[tid] = v;
    __syncthreads();
    for (int off = 1; off < NBMAX; off <<= 1) {
        int t = (tid >= off) ? tmp[tid - off] : 0;
        __syncthreads();
        tmp[tid] += t;
        __syncthreads();
    }
    if (tid < nb) {
        int e = tmp[tid] - v;
        boffs4[dir * (NBMAX + 1) + tid] = e;
        bcur4[dir * NBMAX + tid] = e;
    }
    if (tid == 0) boffs4[dir * (NBMAX + 1) + nb] = nnz;
    if (dir == 0 && tid == 0) { offsE[NS] = nnz; offsO[NP8] = nnz; }
}

// ---------------- A3: staged coalesced bucket scatter (rank-trick) ----------
// pack e.x = other | (lrow << 16), lrow = key & ((1<<rsh)-1)
__global__ __launch_bounds__(256) void staged_scatter(
        const int* __restrict__ key, const int* __restrict__ other,
        const float* __restrict__ vals, int* __restrict__ cursor,
        uint2* __restrict__ edges, int nnz, int rsh) {
    __shared__ int lhist[NBMAX], lofs[NBMAX], lbase[NBMAX];
    __shared__ uint2 stage[TILE];
    __shared__ int   sslot[TILE];
    int tid = threadIdx.x;
    int lmask = (1 << rsh) - 1;
    int ntiles = (nnz + TILE - 1) / TILE;
    for (int tile = blockIdx.x; tile < ntiles; tile += gridDim.x) {
        int tbeg = tile * TILE;
        int n = nnz - tbeg; if (n > TILE) n = TILE;
        lhist[tid] = 0;
        __syncthreads();
        int myb[KPT], myr[KPT]; unsigned myo[KPT]; float myv[KPT];
        #pragma unroll
        for (int g = 0; g < 4; ++g) {
            int s = g * 1024 + tid * 4;           // 4 consecutive edges/thread
            if (s + 4 <= n) {
                int i = tbeg + s;
                int4   k4 = *(const int4*)(key + i);
                int4   o4 = *(const int4*)(other + i);
                float4 v4 = *(const float4*)(vals + i);
                int   kk[4] = {k4.x, k4.y, k4.z, k4.w};
                int   oo[4] = {o4.x, o4.y, o4.z, o4.w};
                float vv[4] = {v4.x, v4.y, v4.z, v4.w};
                #pragma unroll
                for (int k = 0; k < 4; ++k) {
                    int m = g * 4 + k;
                    myb[m] = kk[k] >> rsh;
                    myo[m] = (unsigned)oo[k] | ((unsigned)(kk[k] & lmask) << 16);
                    myv[m] = vv[k];
                    myr[m] = atomicAdd(&lhist[myb[m]], 1);
                }
            } else {
                #pragma unroll
                for (int k = 0; k < 4; ++k) {
                    int m = g * 4 + k;
                    int s2 = s + k;
                    if (s2 < n) {
                        int i = tbeg + s2;
                        int ky = key[i];
                        myb[m] = ky >> rsh;
                        myo[m] = (unsigned)other[i] | ((unsigned)(ky & lmask) << 16);
                        myv[m] = vals[i];
                        myr[m] = atomicAdd(&lhist[myb[m]], 1);
                    } else myb[m] = -1;
                }
            }
        }
        __syncthreads();
        int h = lhist[tid];
        lofs[tid] = h;
        __syncthreads();
        for (int off = 1; off < NBMAX; off <<= 1) {
            int t = (tid >= off) ? lofs[tid - off] : 0;
            __syncthreads();
            lofs[tid] += t;
            __syncthreads();
        }
        lofs[tid] -= h;
        if (h > 0) lbase[tid] = atomicAdd(&cursor[tid], h);
        __syncthreads();
        #pragma unroll
        for (int k = 0; k < KPT; ++k) {
            if (myb[k] >= 0) {
                int ls = lofs[myb[k]] + myr[k];
                stage[ls] = make_uint2(myo[k], __float_as_uint(myv[k]));
                sslot[ls] = lbase[myb[k]] + myr[k];
            }
        }
        __syncthreads();
        #pragma unroll
        for (int k = 0; k < KPT; ++k) {
            int s = k * 256 + tid;
            if (s < n) edges[sslot[s]] = stage[s];
        }
        __syncthreads();
    }
}

// ---------------- B: one block per bucket, 2-pass fine sort -----------------
__global__ __launch_bounds__(512) void row_sort1(
        const uint2* __restrict__ e1, uint2* __restrict__ e2,
        const int* __restrict__ boffs, int* __restrict__ offs,
        int odd, int nb, int rsh, int nrows, unsigned mult8) {
    __shared__ int cnt[BINSMAX];                   // counts, then cursors
    __shared__ int tot[512];
    int tid = threadIdx.x;
    int b = blockIdx.x;
    if (b >= nb) return;
    int bins = odd ? (8 << rsh) : (1 << rsh);      // <= 512
    int beg = boffs[b], end = boffs[b + 1];
    if (tid < bins) cnt[tid] = 0;
    __syncthreads();
    for (int i = beg + tid; i < end; i += 512) {
        uint2 e = e1[i];
        int lrow = (int)(e.x >> 16);
        int bin = odd ? (lrow * 8 + seg8(e.x & 0xFFFFu, mult8)) : lrow;
        atomicAdd(&cnt[bin], 1);
    }
    __syncthreads();
    int own = (tid < bins) ? cnt[tid] : 0;
    tot[tid] = own;
    __syncthreads();
    for (int off = 1; off < 512; off <<= 1) {
        int t = (tid >= off) ? tot[tid - off] : 0;
        __syncthreads();
        tot[tid] += t;
        __syncthreads();
    }
    if (tid < bins) {
        int fineoff = tot[tid] - own;              // exclusive within bucket
        cnt[tid] = beg + fineoff;                  // becomes cursor
        if (!odd) {
            int row = (b << rsh) + tid;
            if (row < nrows) offs[row] = beg + fineoff;
        } else {
            int row = (b << rsh) + (tid >> 3);
            if (row < nrows) offs[(row << 3) + (tid & 7)] = beg + fineoff;
        }
    }
    __syncthreads();
    for (int i = beg + tid; i < end; i += 512) {
        uint2 e = e1[i];
        int lrow = (int)(e.x >> 16);
        int bin = odd ? (lrow * 8 + seg8(e.x & 0xFFFFu, mult8)) : lrow;
        int slot = atomicAdd(&cnt[bin], 1);
        e2[slot] = make_uint2(e.x & 0xFFFFu, e.y);
    }
}

// ---------------- gather core ----------------------------------------------
// chunk_accum: single <=64-edge chunk (rolled 2-stage pipeline, r2 form).
__device__ __forceinline__ void chunk_accum(
        float4& acc, uint2 e, int n, const float* __restrict__ xq, int q) {
    int   c0 = __shfl((int)e.x, q);
    float v0 = __uint_as_float(__shfl((int)e.y, q));
    int   c1 = __shfl((int)e.x, 4 + q);
    float v1 = __uint_as_float(__shfl((int)e.y, 4 + q));
    float4 x0 = *(const float4*)(xq + (((size_t)c0) << 6));
    float4 x1 = *(const float4*)(xq + (((size_t)c1) << 6));
    for (int j = 8; j < n; j += 8) {
        int   nc0 = __shfl((int)e.x, j + q);
        float nv0 = __uint_as_float(__shfl((int)e.y, j + q));
        int   nc1 = __shfl((int)e.x, j + 4 + q);
        float nv1 = __uint_as_float(__shfl((int)e.y, j + 4 + q));
        float4 nx0 = *(const float4*)(xq + (((size_t)nc0) << 6));
        float4 nx1 = *(const float4*)(xq + (((size_t)nc1) << 6));
        acc.x += v0 * x0.x; acc.y += v0 * x0.y;
        acc.z += v0 * x0.z; acc.w += v0 * x0.w;
        acc.x += v1 * x1.x; acc.y += v1 * x1.y;
        acc.z += v1 * x1.z; acc.w += v1 * x1.w;
        v0 = nv0; v1 = nv1; x0 = nx0; x1 = nx1;
    }
    acc.x += v0 * x0.x; acc.y += v0 * x0.y;
    acc.z += v0 * x0.z; acc.w += v0 * x0.w;
    acc.x += v1 * x1.x; acc.y += v1 * x1.y;
    acc.z += v1 * x1.z; acc.w += v1 * x1.w;
}

// chunk_pair: TWO independent bins' first chunks, group-interleaved in ONE
// rolled loop -> 4 independent dwordx4 in flight per iteration (two separate
// dependency chains the compiler cannot re-fuse into a 2-deep chain; r1/r4/r5
// lesson: single-chain deepening fails, independent-chain pairing is the
// compiler-robust form). Common loop to min(nA,nB), per-bin pipelined tails,
// ZERO wasted loads/FMAs. Zero-filled e (empty bin / padded lanes) adds 0.
__device__ __forceinline__ void chunk_pair(
        float4& accA, float4& accB, uint2 eA, uint2 eB, int nA, int nB,
        const float* __restrict__ xq, int q) {
    float vA0 = __uint_as_float(__shfl((int)eA.y, q));
    float vA1 = __uint_as_float(__shfl((int)eA.y, 4 + q));
    float vB0 = __uint_as_float(__shfl((int)eB.y, q));
    float vB1 = __uint_as_float(__shfl((int)eB.y, 4 + q));
    int   cA0 = __shfl((int)eA.x, q);
    int   cA1 = __shfl((int)eA.x, 4 + q);
    int   cB0 = __shfl((int)eB.x, q);
    int   cB1 = __shfl((int)eB.x, 4 + q);
    float4 xA0 = *(const float4*)(xq + (((size_t)cA0) << 6));
    float4 xA1 = *(const float4*)(xq + (((size_t)cA1) << 6));
    float4 xB0 = *(const float4*)(xq + (((size_t)cB0) << 6));
    float4 xB1 = *(const float4*)(xq + (((size_t)cB1) << 6));
    int j = 8;
    for (; j < nA && j < nB; j += 8) {
        int   pA0c = __shfl((int)eA.x, j + q);
        float pA0v = __uint_as_float(__shfl((int)eA.y, j + q));
        int   pA1c = __shfl((int)eA.x, j + 4 + q);
        float pA1v = __uint_as_float(__shfl((int)eA.y, j + 4 + q));
        int   pB0c = __shfl((int)eB.x, j + q);
        float pB0v = __uint_as_float(__shfl((int)eB.y, j + q));
        int   pB1c = __shfl((int)eB.x, j + 4 + q);
        float pB1v = __uint_as_float(__shfl((int)eB.y, j + 4 + q));
        float4 nxA0 = *(const float4*)(xq + (((size_t)pA0c) << 6));
        float4 nxA1 = *(const float4*)(xq + (((size_t)pA1c) << 6));
        float4 nxB0 = *(const float4*)(xq + (((size_t)pB0c) << 6));
        float4 nxB1 = *(const float4*)(xq + (((size_t)pB1c) << 6));
        accA.x += vA0 * xA0.x; accA.y += vA0 * xA0.y;
        accA.z += vA0 * xA0.z; accA.w += vA0 * xA0.w;
        accA.x += vA1 * xA1.x; accA.y += vA1 * xA1.y;
        accA.z += vA1 * xA1.z; accA.w += vA1 * xA1.w;
        accB.x += vB0 * xB0.x; accB.y += vB0 * xB0.y;
        accB.z += vB0 * xB0.z; accB.w += vB0 * xB0.w;
        accB.x += vB1 * xB1.x; accB.y += vB1 * xB1.y;
        accB.z += vB1 * xB1.z; accB.w += vB1 * xB1.w;
        vA0 = pA0v; vA1 = pA1v; xA0 = nxA0; xA1 = nxA1;
        vB0 = pB0v; vB1 = pB1v; xB0 = nxB0; xB1 = nxB1;
    }
    int jA = j, jB = j;
    for (; jA < nA; jA += 8) {                    // A-tail (B exhausted)
        int   nc0 = __shfl((int)eA.x, jA + q);
        float nv0 = __uint_as_float(__shfl((int)eA.y, jA + q));
        int   nc1 = __shfl((int)eA.x, jA + 4 + q);
        float nv1 = __uint_as_float(__shfl((int)eA.y, jA + 4 + q));
        float4 nx0 = *(const float4*)(xq + (((size_t)nc0) << 6));
        float4 nx1 = *(const float4*)(xq + (((size_t)nc1) << 6));
        accA.x += vA0 * xA0.x; accA.y += vA0 * xA0.y;
        accA.z += vA0 * xA0.z; accA.w += vA0 * xA0.w;
        accA.x += vA1 * xA1.x; accA.y += vA1 * xA1.y;
        accA.z += vA1 * xA1.z; accA.w += vA1 * xA1.w;
        vA0 = nv0; vA1 = nv1; xA0 = nx0; xA1 = nx1;
    }
    accA.x += vA0 * xA0.x; accA.y += vA0 * xA0.y;
    accA.z += vA0 * xA0.z; accA.w += vA0 * xA0.w;
    accA.x += vA1 * xA1.x; accA.y += vA1 * xA1.y;
    accA.z += vA1 * xA1.z; accA.w += vA1 * xA1.w;
    for (; jB < nB; jB += 8) {                    // B-tail (A exhausted)
        int   nc0 = __shfl((int)eB.x, jB + q);
        float nv0 = __uint_as_float(__shfl((int)eB.y, jB + q));
        int   nc1 = __shfl((int)eB.x, jB + 4 + q);
        float nv1 = __uint_as_float(__shfl((int)eB.y, jB + 4 + q));
        float4 nx0 = *(const float4*)(xq + (((size_t)nc0) << 6));
        float4 nx1 = *(const float4*)(xq + (((size_t)nc1) << 6));
        accB.x += vB0 * xB0.x; accB.y += vB0 * xB0.y;
        accB.z += vB0 * xB0.z; accB.w += vB0 * xB0.w;
        accB.x += vB1 * xB1.x; accB.y += vB1 * xB1.y;
        accB.z += vB1 * xB1.z; accB.w += vB1 * xB1.w;
        vB0 = nv0; vB1 = nv1; xB0 = nx0; xB1 = nx1;
    }
    accB.x += vB0 * xB0.x; accB.y += vB0 * xB0.y;
    accB.z += vB0 * xB0.z; accB.w += vB0 * xB0.w;
    accB.x += vB1 * xB1.x; accB.y += vB1 * xB1.y;
    accB.z += vB1 * xB1.z; accB.w += vB1 * xB1.w;
}

__device__ __forceinline__ float4 xreduce(float4 a) {
    a.x += __shfl_xor(a.x, 16); a.y += __shfl_xor(a.y, 16);
    a.z += __shfl_xor(a.z, 16); a.w += __shfl_xor(a.w, 16);
    a.x += __shfl_xor(a.x, 32); a.y += __shfl_xor(a.y, 32);
    a.z += __shfl_xor(a.z, 32); a.w += __shfl_xor(a.w, 32);
    return a;
}

// ---------------- C-even: per-row wave gather, 2 rows interleaved -----------
__global__ __launch_bounds__(256) void row_gather(
        const int* __restrict__ offs, const uint2* __restrict__ edges,
        const float* __restrict__ x, float* __restrict__ out, int nrows) {
    int wave = threadIdx.x >> 6, lane = threadIdx.x & 63;
    int q = lane >> 4, l16 = lane & 15;
    const float* xq = x + (l16 << 2);
    int rA = blockIdx.x * 8 + wave * 2;
    if (rA >= nrows) return;
    int rB = rA + 1;
    int begA = offs[rA], endA = offs[rA + 1];
    int begB = 0, endB = 0;
    if (rB < nrows) { begB = offs[rB]; endB = offs[rB + 1]; }
    int nA = endA - begA; if (nA > 64) nA = 64;
    int nB = endB - begB; if (nB > 64) nB = 64;
    uint2 eA = make_uint2(0u, 0u), eB = make_uint2(0u, 0u);
    if (lane < nA) eA = edges[begA + lane];
    if (lane < nB) eB = edges[begB + lane];
    float4 accA = make_float4(0.f, 0.f, 0.f, 0.f);
    float4 accB = make_float4(0.f, 0.f, 0.f, 0.f);
    chunk_pair(accA, accB, eA, eB, nA, nB, xq, q);
    for (int base = begA + 64; base < endA; base += 64) {
        int n = endA - base; if (n > 64) n = 64;
        uint2 e = make_uint2(0u, 0u);
        if (lane < n) e = edges[base + lane];
        chunk_accum(accA, e, n, xq, q);
    }
    for (int base = begB + 64; base < endB; base += 64) {
        int n = endB - base; if (n > 64) n = 64;
        uint2 e = make_uint2(0u, 0u);
        if (lane < n) e = edges[base + lane];
        chunk_accum(accB, e, n, xq, q);
    }
    accA = xreduce(accA);
    if ((lane >> 4) == 0)
        *(float4*)(out + (((size_t)rA) << 6) + (l16 << 2)) = accA;
    if (rB < nrows) {
        accB = xreduce(accB);
        if ((lane >> 4) == 0)
            *(float4*)(out + (((size_t)rB) << 6) + (l16 << 2)) = accB;
    }
}

// ---------------- C-odd: XCD-partitioned gather, 2 bins interleaved ---------
__global__ __launch_bounds__(256) void xcd_gather(
        const int* __restrict__ offs, const uint2* __restrict__ edges,
        const float* __restrict__ x, float* __restrict__ partial, int NP) {
    int g = blockIdx.x;
    int slot = g & 7;
    int t = g >> 3;
    int wave = threadIdx.x >> 6, lane = threadIdx.x & 63;
    int q = lane >> 4, l16 = lane & 15;
    const float* xq = x + (l16 << 2);
    int rA = t * 8 + wave * 2;
    if (rA >= NP) return;
    int rB = rA + 1;
    int binA = rA * 8 + slot;
    int begA = offs[binA], endA = offs[binA + 1];
    int begB = 0, endB = 0;
    if (rB < NP) { int binB = rB * 8 + slot; begB = offs[binB]; endB = offs[binB + 1]; }
    int nA = endA - begA; if (nA > 64) nA = 64;
    int nB = endB - begB; if (nB > 64) nB = 64;
    uint2 eA = make_uint2(0u, 0u), eB = make_uint2(0u, 0u);
    if (lane < nA) eA = edges[begA + lane];
    if (lane < nB) eB = edges[begB + lane];
    float4 accA = make_float4(0.f, 0.f, 0.f, 0.f);
    float4 accB = make_float4(0.f, 0.f, 0.f, 0.f);
    chunk_pair(accA, accB, eA, eB, nA, nB, xq, q);
    for (int base = begA + 64; base < endA; base += 64) {
        int n = endA - base; if (n > 64) n = 64;
        uint2 e = make_uint2(0u, 0u);
        if (lane < n) e = edges[base + lane];
        chunk_accum(accA, e, n, xq, q);
    }
    for (int base = begB + 64; base < endB; base += 64) {
        int n = endB - base; if (n > 64) n = 64;
        uint2 e = make_uint2(0u, 0u);
        if (lane < n) e = edges[base + lane];
        chunk_accum(accB, e, n, xq, q);
    }
    accA = xreduce(accA);
    if ((lane >> 4) == 0)
        *(float4*)(partial + (size_t)slot * NP * 64 + (((size_t)rA) << 6) + (l16 << 2)) = accA;
    if (rB < NP) {
        accB = xreduce(accB);
        if ((lane >> 4) == 0)
            *(float4*)(partial + (size_t)slot * NP * 64 + (((size_t)rB) << 6) + (l16 << 2)) = accB;
    }
}

__global__ __launch_bounds__(256) void reduce8(
        const float* __restrict__ partial, float* __restrict__ out, int n4) {
    int i = blockIdx.x * 256 + threadIdx.x;
    if (i < n4) {
        const float4* p = (const float4*)partial;
        float4 s = make_float4(0.f, 0.f, 0.f, 0.f);
        #pragma unroll
        for (int xx = 0; xx < 8; ++xx) {
            float4 v = p[(size_t)xx * n4 + i];
            s.x += v.x; s.y += v.y; s.z += v.z; s.w += v.w;
        }
        ((float4*)out)[i] = s;
    }
}

// ---------------- fallback: atomic scatter ----------------
__global__ void spmm_scatter_kernel(const int* __restrict__ rows, const int* __restrict__ cols,
                                    const float* __restrict__ vals,
                                    const float* __restrict__ s_emb, const float* __restrict__ p_emb,
                                    float* __restrict__ out_s, float* __restrict__ out_p, int nnz) {
    long long t = (long long)blockIdx.x * blockDim.x + threadIdx.x;
    int e = (int)(t >> 6);
    int d = (int)(t & 63);
    if (e >= nnz) return;
    int r = rows[e];
    int c = cols[e];
    float v = vals[e];
    atomicAdd(&out_s[(size_t)r * 64 + d], v * p_emb[(size_t)c * 64 + d]);
    atomicAdd(&out_p[(size_t)c * 64 + d], v * s_emb[(size_t)r * 64 + d]);
}

// ---------------- host ----------------
extern "C" void kernel_launch(void* const* d_in, const int* in_sizes, int n_in,
                              void* d_out, int out_size, void* d_ws, size_t ws_size,
                              hipStream_t stream) {
    const float* s_emb   = (const float*)d_in[0];
    const float* p_emb   = (const float*)d_in[1];
    const int*   a_rows  = (const int*)d_in[2];
    const int*   a_cols  = (const int*)d_in[3];
    const float* a_vals  = (const float*)d_in[4];
    const int*   ia_rows = (const int*)d_in[5];
    const int*   ia_cols = (const int*)d_in[6];
    const float* ia_vals = (const float*)d_in[7];

    const int NS  = in_sizes[0] / 64;
    const int NP  = in_sizes[1] / 64;
    const int nnz = in_sizes[2];
    const int NP8 = NP * 8;

    float* out = (float*)d_out;
    float* out_sc  = out;
    float* out_sic = out_sc  + (size_t)NS * 64;
    float* out_pc  = out_sic + (size_t)NS * 64;
    float* out_pic = out_pc  + (size_t)NP * 64;

    int rsh_s = 0; while ((((long long)NS + (1LL << rsh_s) - 1) >> rsh_s) > NBMAX) rsh_s++;
    int rsh_p = 0; while ((((long long)NP + (1LL << rsh_p) - 1) >> rsh_p) > NBMAX) rsh_p++;
    int nb_s = (NS + (1 << rsh_s) - 1) >> rsh_s;
    int nb_p = (NP + (1 << rsh_p) - 1) >> rsh_p;
    unsigned mult8 = (unsigned)((8ULL << 32) / (unsigned)NS);

    const size_t edges_bytes = (size_t)nnz * sizeof(uint2);
    const size_t offsE_bytes = (size_t)(NS + 1) * sizeof(int);
    const size_t offsO_bytes = (size_t)(NP8 + 1) * sizeof(int);
    const size_t need = 2 * edges_bytes + offsE_bytes + offsO_bytes
                      + (size_t)(4 * NBMAX + 4 * (NBMAX + 1) + 4 * NBMAX) * sizeof(int) + 256;
    const bool packable = (NS <= 0xFFFF) && (NP <= 0xFFFF) &&
                          ((1 << rsh_s) <= BINSMAX) && ((8 << rsh_p) <= BINSMAX) &&
                          (edges_bytes >= (size_t)NP8 * 64 * sizeof(float)) &&
                          ((NP * 64) % 4 == 0);

    if (ws_size < need || !packable) {
        hipMemsetAsync(d_out, 0, (size_t)out_size * sizeof(float), stream);
        const long long total = (long long)nnz * 64;
        const int grid = (int)((total + 255) / 256);
        spmm_scatter_kernel<<<grid, 256, 0, stream>>>(a_rows, a_cols, a_vals, s_emb, p_emb,
                                                      out_sc, out_pc, nnz);
        spmm_scatter_kernel<<<grid, 256, 0, stream>>>(ia_rows, ia_cols, ia_vals, s_emb, p_emb,
                                                      out_sic, out_pic, nnz);
        return;
    }

    char* w = (char*)d_ws;
    uint2* edges1 = (uint2*)w;  w += edges_bytes;     // aliased as `partial` in odd gathers
    uint2* edges2 = (uint2*)w;  w += edges_bytes;
    int*   offsE  = (int*)w;    w += offsE_bytes;
    int*   offsO  = (int*)w;    w += offsO_bytes;
    int*   gcnt4  = (int*)w;    w += 4 * NBMAX * sizeof(int);
    int*   boffs4 = (int*)w;    w += 4 * (NBMAX + 1) * sizeof(int);
    int*   bcur4  = (int*)w;
    float* partial = (float*)edges1;

    hipMemsetAsync(gcnt4, 0, 4 * NBMAX * sizeof(int), stream);
    // dirs: 0 = a by row, 1 = a by col, 2 = ia by row, 3 = ia by col
    hist_all<<<1024, 256, 0, stream>>>(a_rows, a_cols, ia_rows, ia_cols,
                                       gcnt4, nnz, rsh_s, rsh_p);
    scan_all<<<4, 256, 0, stream>>>(gcnt4, boffs4, bcur4, nb_s, nb_p, nnz,
                                    offsE, offsO, NS, NP8);

    const int ntiles = (nnz + TILE - 1) / TILE;

    struct Dir { const int* key; const int* other; const float* vals;
                 float* out; int odd; };
    // output order: (student_c, student_ic, problem_c, problem_ic)
    Dir dirs[4] = {
        { a_rows,  a_cols,  a_vals,  out_sc,  0 },
        { a_cols,  a_rows,  a_vals,  out_pc,  1 },
        { ia_rows, ia_cols, ia_vals, out_sic, 0 },
        { ia_cols, ia_rows, ia_vals, out_pic, 1 },
    };
    for (int t = 0; t < 4; ++t) {
        const Dir& D = dirs[t];
        if (!D.odd) {
            staged_scatter<<<ntiles, 256, 0, stream>>>(D.key, D.other, D.vals,
                                                       bcur4 + t * NBMAX, edges1, nnz, rsh_s);
            row_sort1<<<nb_s, 512, 0, stream>>>(edges1, edges2,
                                                boffs4 + t * (NBMAX + 1), offsE,
                                                0, nb_s, rsh_s, NS, mult8);
            row_gather<<<(NS + 7) / 8, 256, 0, stream>>>(offsE, edges2, p_emb, D.out, NS);
        } else {
            staged_scatter<<<ntiles, 256, 0, stream>>>(D.key, D.other, D.vals,
                                                       bcur4 + t * NBMAX, edges1, nnz, rsh_p);
            row_sort1<<<nb_p, 512, 0, stream>>>(edges1, edges2,
                                                boffs4 + t * (NBMAX + 1), offsO,
                                                1, nb_p, rsh_p, NP, mult8);
            xcd_gather<<<8 * ((NP + 7) / 8), 256, 0, stream>>>(offsO, edges2,
                                                               s_emb, partial, NP);
            reduce8<<<(NP * 64 / 4 + 255) / 256, 256, 0, stream>>>(partial, D.out, NP * 64 / 4);
        }
    }
}

// Round 10
// 557.967 us; speedup vs baseline: 1.0452x; 1.0452x over previous
//
#include <hip/hip_runtime.h>
#include <hip/hip_bf16.h>

#define NBMAX 256   // coarse buckets per direction
#define TILE  4096  // edges per staged-scatter tile (per-dir fallback)
#define KPT   16    // TILE / 256
#define FTILE 2048  // edges per fused-scatter tile
#define FKPT  8     // FTILE / 256
#define BINSMAX 512 // max fine bins per bucket

// seg(student) in [0,8): near-uniform 8-way split via magic multiply
__device__ __forceinline__ int seg8(unsigned r, unsigned mult8) {
    return (int)__umulhi(r, mult8);
}

// ---------------- A1: coarse histogram, all 4 dirs (LDS-privatized) ---------
__global__ __launch_bounds__(256) void hist_all(
        const int* __restrict__ k0, const int* __restrict__ k1,
        const int* __restrict__ k2, const int* __restrict__ k3,
        int* __restrict__ gcnt4, int nnz, int rsh_s, int rsh_p) {
    __shared__ int h[NBMAX];
    int dir = blockIdx.x & 3;
    const int* key = (dir == 0) ? k0 : (dir == 1) ? k1 : (dir == 2) ? k2 : k3;
    int rsh = (dir & 1) ? rsh_p : rsh_s;
    h[threadIdx.x] = 0;
    __syncthreads();
    int ch = blockIdx.x >> 2, nch = gridDim.x >> 2;
    int nnz4 = nnz >> 2;
    for (int i = ch * 256 + threadIdx.x; i < nnz4; i += nch * 256) {
        int4 k4 = ((const int4*)key)[i];
        atomicAdd(&h[k4.x >> rsh], 1);
        atomicAdd(&h[k4.y >> rsh], 1);
        atomicAdd(&h[k4.z >> rsh], 1);
        atomicAdd(&h[k4.w >> rsh], 1);
    }
    if (ch == 0) {
        for (int i = (nnz4 << 2) + threadIdx.x; i < nnz; i += 256)
            atomicAdd(&h[key[i] >> rsh], 1);
    }
    __syncthreads();
    int v = h[threadIdx.x];
    if (v) atomicAdd(&gcnt4[dir * NBMAX + threadIdx.x], v);
}

// ---------------- A2: bucket offsets for all 4 dirs (4 blocks) --------------
__global__ __launch_bounds__(256) void scan_all(
        const int* __restrict__ gcnt4, int* __restrict__ boffs4,
        int* __restrict__ bcur4, int nb_s, int nb_p, int nnz,
        int* __restrict__ offsE, int* __restrict__ offsO, int NS, int NP8) {
    __shared__ int tmp[NBMAX];
    int dir = blockIdx.x, tid = threadIdx.x;
    int nb = (dir & 1) ? nb_p : nb_s;
    int v = (tid < nb) ? gcnt4[dir * NBMAX + tid] : 0;
    tmp[tid] = v;
    __syncthreads();
    for (int off = 1; off < NBMAX; off <<= 1) {
        int t = (tid >= off) ? tmp[tid - off] : 0;
        __syncthreads();
        tmp[tid] += t;
        __syncthreads();
    }
    if (tid < nb) {
        int e = tmp[tid] - v;
        boffs4[dir * (NBMAX + 1) + tid] = e;
        bcur4[dir * NBMAX + tid] = e;
    }
    if (tid == 0) boffs4[dir * (NBMAX + 1) + nb] = nnz;
    if (dir == 0 && tid == 0) { offsE[NS] = nnz; offsO[NP8] = nnz; }
}

// ---------------- A3a: per-dir staged scatter (fallback when ws is tight) ---
__global__ __launch_bounds__(256) void staged_scatter(
        const int* __restrict__ key, const int* __restrict__ other,
        const float* __restrict__ vals, int* __restrict__ cursor,
        uint2* __restrict__ edges, int nnz, int rsh) {
    __shared__ int lhist[NBMAX], lofs[NBMAX], lbase[NBMAX];
    __shared__ uint2 stage[TILE];
    __shared__ int   sslot[TILE];
    int tid = threadIdx.x;
    int lmask = (1 << rsh) - 1;
    int ntiles = (nnz + TILE - 1) / TILE;
    for (int tile = blockIdx.x; tile < ntiles; tile += gridDim.x) {
        int tbeg = tile * TILE;
        int n = nnz - tbeg; if (n > TILE) n = TILE;
        lhist[tid] = 0;
        __syncthreads();
        int myb[KPT], myr[KPT]; unsigned myo[KPT]; float myv[KPT];
        #pragma unroll
        for (int g = 0; g < 4; ++g) {
            int s = g * 1024 + tid * 4;
            if (s + 4 <= n) {
                int i = tbeg + s;
                int4   k4 = *(const int4*)(key + i);
                int4   o4 = *(const int4*)(other + i);
                float4 v4 = *(const float4*)(vals + i);
                int   kk[4] = {k4.x, k4.y, k4.z, k4.w};
                int   oo[4] = {o4.x, o4.y, o4.z, o4.w};
                float vv[4] = {v4.x, v4.y, v4.z, v4.w};
                #pragma unroll
                for (int k = 0; k < 4; ++k) {
                    int m = g * 4 + k;
                    myb[m] = kk[k] >> rsh;
                    myo[m] = (unsigned)oo[k] | ((unsigned)(kk[k] & lmask) << 16);
                    myv[m] = vv[k];
                    myr[m] = atomicAdd(&lhist[myb[m]], 1);
                }
            } else {
                #pragma unroll
                for (int k = 0; k < 4; ++k) {
                    int m = g * 4 + k;
                    int s2 = s + k;
                    if (s2 < n) {
                        int i = tbeg + s2;
                        int ky = key[i];
                        myb[m] = ky >> rsh;
                        myo[m] = (unsigned)other[i] | ((unsigned)(ky & lmask) << 16);
                        myv[m] = vals[i];
                        myr[m] = atomicAdd(&lhist[myb[m]], 1);
                    } else myb[m] = -1;
                }
            }
        }
        __syncthreads();
        int h = lhist[tid];
        lofs[tid] = h;
        __syncthreads();
        for (int off = 1; off < NBMAX; off <<= 1) {
            int t = (tid >= off) ? lofs[tid - off] : 0;
            __syncthreads();
            lofs[tid] += t;
            __syncthreads();
        }
        lofs[tid] -= h;
        if (h > 0) lbase[tid] = atomicAdd(&cursor[tid], h);
        __syncthreads();
        #pragma unroll
        for (int k = 0; k < KPT; ++k) {
            if (myb[k] >= 0) {
                int ls = lofs[myb[k]] + myr[k];
                stage[ls] = make_uint2(myo[k], __float_as_uint(myv[k]));
                sslot[ls] = lbase[myb[k]] + myr[k];
            }
        }
        __syncthreads();
        #pragma unroll
        for (int k = 0; k < KPT; ++k) {
            int s = k * 256 + tid;
            if (s < n) edges[sslot[s]] = stage[s];
        }
        __syncthreads();
    }
}

// ---------------- A3b: FUSED scatter - one read of (rows,cols,vals) feeds
// BOTH directions of a matrix (r9 theory: halves the 2x input re-read, halves
// tile-loop fixed cost). Even: key=row (rsh_e), odd: key=col (rsh_o).
__global__ __launch_bounds__(256) void staged_scatter2(
        const int* __restrict__ krow, const int* __restrict__ kcol,
        const float* __restrict__ vals,
        int* __restrict__ curE, int* __restrict__ curO,
        uint2* __restrict__ edgesE, uint2* __restrict__ edgesO,
        int nnz, int rsh_e, int rsh_o) {
    __shared__ int lhistE[NBMAX], lofsE[NBMAX], lbaseE[NBMAX];
    __shared__ int lhistO[NBMAX], lofsO[NBMAX], lbaseO[NBMAX];
    __shared__ uint2 stageE[FTILE], stageO[FTILE];
    __shared__ int   sslotE[FTILE], sslotO[FTILE];
    int tid = threadIdx.x;
    int lmE = (1 << rsh_e) - 1, lmO = (1 << rsh_o) - 1;
    int ntiles = (nnz + FTILE - 1) / FTILE;
    for (int tile = blockIdx.x; tile < ntiles; tile += gridDim.x) {
        int tbeg = tile * FTILE;
        int n = nnz - tbeg; if (n > FTILE) n = FTILE;
        lhistE[tid] = 0; lhistO[tid] = 0;
        __syncthreads();
        int mbE[FKPT], mrE[FKPT]; unsigned moE[FKPT];
        int mbO[FKPT], mrO[FKPT]; unsigned moO[FKPT];
        float mv[FKPT];
        #pragma unroll
        for (int g = 0; g < 2; ++g) {
            int s = g * 1024 + tid * 4;           // 4 consecutive edges/thread
            if (s + 4 <= n) {
                int i = tbeg + s;
                int4   r4 = *(const int4*)(krow + i);
                int4   c4 = *(const int4*)(kcol + i);
                float4 v4 = *(const float4*)(vals + i);
                int   rr[4] = {r4.x, r4.y, r4.z, r4.w};
                int   cc[4] = {c4.x, c4.y, c4.z, c4.w};
                float vv[4] = {v4.x, v4.y, v4.z, v4.w};
                #pragma unroll
                for (int k = 0; k < 4; ++k) {
                    int m = g * 4 + k;
                    mv[m]  = vv[k];
                    mbE[m] = rr[k] >> rsh_e;
                    moE[m] = (unsigned)cc[k] | ((unsigned)(rr[k] & lmE) << 16);
                    mrE[m] = atomicAdd(&lhistE[mbE[m]], 1);
                    mbO[m] = cc[k] >> rsh_o;
                    moO[m] = (unsigned)rr[k] | ((unsigned)(cc[k] & lmO) << 16);
                    mrO[m] = atomicAdd(&lhistO[mbO[m]], 1);
                }
            } else {
                #pragma unroll
                for (int k = 0; k < 4; ++k) {
                    int m = g * 4 + k;
                    int s2 = s + k;
                    if (s2 < n) {
                        int i = tbeg + s2;
                        int r = krow[i], c = kcol[i];
                        mv[m]  = vals[i];
                        mbE[m] = r >> rsh_e;
                        moE[m] = (unsigned)c | ((unsigned)(r & lmE) << 16);
                        mrE[m] = atomicAdd(&lhistE[mbE[m]], 1);
                        mbO[m] = c >> rsh_o;
                        moO[m] = (unsigned)r | ((unsigned)(c & lmO) << 16);
                        mrO[m] = atomicAdd(&lhistO[mbO[m]], 1);
                    } else { mbE[m] = -1; mbO[m] = -1; }
                }
            }
        }
        __syncthreads();
        int hE = lhistE[tid], hO = lhistO[tid];
        lofsE[tid] = hE; lofsO[tid] = hO;
        __syncthreads();
        for (int off = 1; off < NBMAX; off <<= 1) {
            int tE = (tid >= off) ? lofsE[tid - off] : 0;
            int tO = (tid >= off) ? lofsO[tid - off] : 0;
            __syncthreads();
            lofsE[tid] += tE; lofsO[tid] += tO;
            __syncthreads();
        }
        lofsE[tid] -= hE; lofsO[tid] -= hO;
        if (hE > 0) lbaseE[tid] = atomicAdd(&curE[tid], hE);
        if (hO > 0) lbaseO[tid] = atomicAdd(&curO[tid], hO);
        __syncthreads();
        #pragma unroll
        for (int k = 0; k < FKPT; ++k) {
            if (mbE[k] >= 0) {
                int lsE = lofsE[mbE[k]] + mrE[k];
                stageE[lsE] = make_uint2(moE[k], __float_as_uint(mv[k]));
                sslotE[lsE] = lbaseE[mbE[k]] + mrE[k];
                int lsO = lofsO[mbO[k]] + mrO[k];
                stageO[lsO] = make_uint2(moO[k], __float_as_uint(mv[k]));
                sslotO[lsO] = lbaseO[mbO[k]] + mrO[k];
            }
        }
        __syncthreads();
        #pragma unroll
        for (int k = 0; k < FKPT; ++k) {
            int s = k * 256 + tid;
            if (s < n) {
                edgesE[sslotE[s]] = stageE[s];
                edgesO[sslotO[s]] = stageO[s];
            }
        }
        __syncthreads();
    }
}

// ---------------- B: one block per bucket, 2-pass fine sort -----------------
__global__ __launch_bounds__(512) void row_sort1(
        const uint2* __restrict__ e1, uint2* __restrict__ e2,
        const int* __restrict__ boffs, int* __restrict__ offs,
        int odd, int nb, int rsh, int nrows, unsigned mult8) {
    __shared__ int cnt[BINSMAX];                   // counts, then cursors
    __shared__ int tot[512];
    int tid = threadIdx.x;
    int b = blockIdx.x;
    if (b >= nb) return;
    int bins = odd ? (8 << rsh) : (1 << rsh);      // <= 512
    int beg = boffs[b], end = boffs[b + 1];
    if (tid < bins) cnt[tid] = 0;
    __syncthreads();
    for (int i = beg + tid; i < end; i += 512) {
        uint2 e = e1[i];
        int lrow = (int)(e.x >> 16);
        int bin = odd ? (lrow * 8 + seg8(e.x & 0xFFFFu, mult8)) : lrow;
        atomicAdd(&cnt[bin], 1);
    }
    __syncthreads();
    int own = (tid < bins) ? cnt[tid] : 0;
    tot[tid] = own;
    __syncthreads();
    for (int off = 1; off < 512; off <<= 1) {
        int t = (tid >= off) ? tot[tid - off] : 0;
        __syncthreads();
        tot[tid] += t;
        __syncthreads();
    }
    if (tid < bins) {
        int fineoff = tot[tid] - own;              // exclusive within bucket
        cnt[tid] = beg + fineoff;                  // becomes cursor
        if (!odd) {
            int row = (b << rsh) + tid;
            if (row < nrows) offs[row] = beg + fineoff;
        } else {
            int row = (b << rsh) + (tid >> 3);
            if (row < nrows) offs[(row << 3) + (tid & 7)] = beg + fineoff;
        }
    }
    __syncthreads();
    for (int i = beg + tid; i < end; i += 512) {
        uint2 e = e1[i];
        int lrow = (int)(e.x >> 16);
        int bin = odd ? (lrow * 8 + seg8(e.x & 0xFFFFu, mult8)) : lrow;
        int slot = atomicAdd(&cnt[bin], 1);
        e2[slot] = make_uint2(e.x & 0xFFFFu, e.y);
    }
}

// ---------------- gather core (r8 form - L2-BW-pinned, do not touch) --------
__device__ __forceinline__ void chunk_accum(
        float4& acc, uint2 e, int n, const float* __restrict__ xq, int q) {
    int   c0 = __shfl((int)e.x, q);
    float v0 = __uint_as_float(__shfl((int)e.y, q));
    int   c1 = __shfl((int)e.x, 4 + q);
    float v1 = __uint_as_float(__shfl((int)e.y, 4 + q));
    float4 x0 = *(const float4*)(xq + (((size_t)c0) << 6));
    float4 x1 = *(const float4*)(xq + (((size_t)c1) << 6));
    for (int j = 8; j < n; j += 8) {
        int   nc0 = __shfl((int)e.x, j + q);
        float nv0 = __uint_as_float(__shfl((int)e.y, j + q));
        int   nc1 = __shfl((int)e.x, j + 4 + q);
        float nv1 = __uint_as_float(__shfl((int)e.y, j + 4 + q));
        float4 nx0 = *(const float4*)(xq + (((size_t)nc0) << 6));
        float4 nx1 = *(const float4*)(xq + (((size_t)nc1) << 6));
        acc.x += v0 * x0.x; acc.y += v0 * x0.y;
        acc.z += v0 * x0.z; acc.w += v0 * x0.w;
        acc.x += v1 * x1.x; acc.y += v1 * x1.y;
        acc.z += v1 * x1.z; acc.w += v1 * x1.w;
        v0 = nv0; v1 = nv1; x0 = nx0; x1 = nx1;
    }
    acc.x += v0 * x0.x; acc.y += v0 * x0.y;
    acc.z += v0 * x0.z; acc.w += v0 * x0.w;
    acc.x += v1 * x1.x; acc.y += v1 * x1.y;
    acc.z += v1 * x1.z; acc.w += v1 * x1.w;
}

__device__ __forceinline__ float4 gather_pre(
        uint2 e0, int beg, int end, const uint2* __restrict__ edges,
        const float* __restrict__ xq, int q, int lane) {
    float4 acc = make_float4(0.f, 0.f, 0.f, 0.f);
    int n0 = end - beg; if (n0 > 64) n0 = 64;
    chunk_accum(acc, e0, n0, xq, q);              // empty bin: e0 zero -> +0
    for (int base = beg + 64; base < end; base += 64) {
        int n = end - base; if (n > 64) n = 64;
        uint2 e = make_uint2(0u, 0u);
        if (lane < n) e = edges[base + lane];
        chunk_accum(acc, e, n, xq, q);
    }
    acc.x += __shfl_xor(acc.x, 16); acc.y += __shfl_xor(acc.y, 16);
    acc.z += __shfl_xor(acc.z, 16); acc.w += __shfl_xor(acc.w, 16);
    acc.x += __shfl_xor(acc.x, 32); acc.y += __shfl_xor(acc.y, 32);
    acc.z += __shfl_xor(acc.z, 32); acc.w += __shfl_xor(acc.w, 32);
    return acc;
}

// ---------------- C-even: per-row wave gather, 2 rows/wave pipelined --------
__global__ __launch_bounds__(256) void row_gather(
        const int* __restrict__ offs, const uint2* __restrict__ edges,
        const float* __restrict__ x, float* __restrict__ out, int nrows) {
    int wave = threadIdx.x >> 6, lane = threadIdx.x & 63;
    int q = lane >> 4, l16 = lane & 15;
    const float* xq = x + (l16 << 2);
    int rA = blockIdx.x * 8 + wave * 2;
    if (rA >= nrows) return;
    int rB = rA + 1;
    int begA = offs[rA], endA = offs[rA + 1];
    int begB = 0, endB = 0;
    if (rB < nrows) { begB = offs[rB]; endB = offs[rB + 1]; }
    int nA = endA - begA; if (nA > 64) nA = 64;
    int nB = endB - begB; if (nB > 64) nB = 64;
    uint2 eA = make_uint2(0u, 0u), eB = make_uint2(0u, 0u);
    if (lane < nA) eA = edges[begA + lane];
    if (lane < nB) eB = edges[begB + lane];     // in flight during A's compute
    float4 accA = gather_pre(eA, begA, endA, edges, xq, q, lane);
    if ((lane >> 4) == 0)
        *(float4*)(out + (((size_t)rA) << 6) + (l16 << 2)) = accA;
    if (rB < nrows) {
        float4 accB = gather_pre(eB, begB, endB, edges, xq, q, lane);
        if ((lane >> 4) == 0)
            *(float4*)(out + (((size_t)rB) << 6) + (l16 << 2)) = accB;
    }
}

// ---------------- C-odd: XCD-partitioned gather, 2 bins/wave pipelined ------
__global__ __launch_bounds__(256) void xcd_gather(
        const int* __restrict__ offs, const uint2* __restrict__ edges,
        const float* __restrict__ x, float* __restrict__ partial, int NP) {
    int g = blockIdx.x;
    int slot = g & 7;
    int t = g >> 3;
    int wave = threadIdx.x >> 6, lane = threadIdx.x & 63;
    int q = lane >> 4, l16 = lane & 15;
    const float* xq = x + (l16 << 2);
    int rA = t * 8 + wave * 2;
    if (rA >= NP) return;
    int rB = rA + 1;
    int binA = rA * 8 + slot;
    int begA = offs[binA], endA = offs[binA + 1];
    int begB = 0, endB = 0;
    if (rB < NP) { int binB = rB * 8 + slot; begB = offs[binB]; endB = offs[binB + 1]; }
    int nA = endA - begA; if (nA > 64) nA = 64;
    int nB = endB - begB; if (nB > 64) nB = 64;
    uint2 eA = make_uint2(0u, 0u), eB = make_uint2(0u, 0u);
    if (lane < nA) eA = edges[begA + lane];
    if (lane < nB) eB = edges[begB + lane];     // in flight during A's compute
    float4 accA = gather_pre(eA, begA, endA, edges, xq, q, lane);
    if ((lane >> 4) == 0)
        *(float4*)(partial + (size_t)slot * NP * 64 + (((size_t)rA) << 6) + (l16 << 2)) = accA;
    if (rB < NP) {
        float4 accB = gather_pre(eB, begB, endB, edges, xq, q, lane);
        if ((lane >> 4) == 0)
            *(float4*)(partial + (size_t)slot * NP * 64 + (((size_t)rB) << 6) + (l16 << 2)) = accB;
    }
}

__global__ __launch_bounds__(256) void reduce8(
        const float* __restrict__ partial, float* __restrict__ out, int n4) {
    int i = blockIdx.x * 256 + threadIdx.x;
    if (i < n4) {
        const float4* p = (const float4*)partial;
        float4 s = make_float4(0.f, 0.f, 0.f, 0.f);
        #pragma unroll
        for (int xx = 0; xx < 8; ++xx) {
            float4 v = p[(size_t)xx * n4 + i];
            s.x += v.x; s.y += v.y; s.z += v.z; s.w += v.w;
        }
        ((float4*)out)[i] = s;
    }
}

// ---------------- fallback: atomic scatter ----------------
__global__ void spmm_scatter_kernel(const int* __restrict__ rows, const int* __restrict__ cols,
                                    const float* __restrict__ vals,
                                    const float* __restrict__ s_emb, const float* __restrict__ p_emb,
                                    float* __restrict__ out_s, float* __restrict__ out_p, int nnz) {
    long long t = (long long)blockIdx.x * blockDim.x + threadIdx.x;
    int e = (int)(t >> 6);
    int d = (int)(t & 63);
    if (e >= nnz) return;
    int r = rows[e];
    int c = cols[e];
    float v = vals[e];
    atomicAdd(&out_s[(size_t)r * 64 + d], v * p_emb[(size_t)c * 64 + d]);
    atomicAdd(&out_p[(size_t)c * 64 + d], v * s_emb[(size_t)r * 64 + d]);
}

// ---------------- host ----------------
extern "C" void kernel_launch(void* const* d_in, const int* in_sizes, int n_in,
                              void* d_out, int out_size, void* d_ws, size_t ws_size,
                              hipStream_t stream) {
    const float* s_emb   = (const float*)d_in[0];
    const float* p_emb   = (const float*)d_in[1];
    const int*   a_rows  = (const int*)d_in[2];
    const int*   a_cols  = (const int*)d_in[3];
    const float* a_vals  = (const float*)d_in[4];
    const int*   ia_rows = (const int*)d_in[5];
    const int*   ia_cols = (const int*)d_in[6];
    const float* ia_vals = (const float*)d_in[7];

    const int NS  = in_sizes[0] / 64;
    const int NP  = in_sizes[1] / 64;
    const int nnz = in_sizes[2];
    const int NP8 = NP * 8;

    float* out = (float*)d_out;
    float* out_sc  = out;
    float* out_sic = out_sc  + (size_t)NS * 64;
    float* out_pc  = out_sic + (size_t)NS * 64;
    float* out_pic = out_pc  + (size_t)NP * 64;

    int rsh_s = 0; while ((((long long)NS + (1LL << rsh_s) - 1) >> rsh_s) > NBMAX) rsh_s++;
    int rsh_p = 0; while ((((long long)NP + (1LL << rsh_p) - 1) >> rsh_p) > NBMAX) rsh_p++;
    int nb_s = (NS + (1 << rsh_s) - 1) >> rsh_s;
    int nb_p = (NP + (1 << rsh_p) - 1) >> rsh_p;
    unsigned mult8 = (unsigned)((8ULL << 32) / (unsigned)NS);

    const size_t edges_bytes = (size_t)nnz * sizeof(uint2);
    const size_t offsE_bytes = (size_t)(NS + 1) * sizeof(int);
    const size_t offsO_bytes = (size_t)(NP8 + 1) * sizeof(int);
    const size_t fixed_bytes = offsE_bytes + offsO_bytes
                      + (size_t)(4 * NBMAX + 4 * (NBMAX + 1) + 4 * NBMAX) * sizeof(int) + 256;
    const size_t need  = 2 * edges_bytes + fixed_bytes;
    const size_t need3 = 3 * edges_bytes + fixed_bytes;
    const bool packable = (NS <= 0xFFFF) && (NP <= 0xFFFF) &&
                          ((1 << rsh_s) <= BINSMAX) && ((8 << rsh_p) <= BINSMAX) &&
                          (edges_bytes >= (size_t)NP8 * 64 * sizeof(float)) &&
                          ((NP * 64) % 4 == 0);

    if (ws_size < need || !packable) {
        hipMemsetAsync(d_out, 0, (size_t)out_size * sizeof(float), stream);
        const long long total = (long long)nnz * 64;
        const int grid = (int)((total + 255) / 256);
        spmm_scatter_kernel<<<grid, 256, 0, stream>>>(a_rows, a_cols, a_vals, s_emb, p_emb,
                                                      out_sc, out_pc, nnz);
        spmm_scatter_kernel<<<grid, 256, 0, stream>>>(ia_rows, ia_cols, ia_vals, s_emb, p_emb,
                                                      out_sic, out_pic, nnz);
        return;
    }

    const bool fused = (ws_size >= need3);

    char* w = (char*)d_ws;
    uint2* edges1 = (uint2*)w;  w += edges_bytes;
    uint2* edges2 = (uint2*)w;  w += edges_bytes;
    uint2* edges3 = nullptr;
    if (fused) { edges3 = (uint2*)w; w += edges_bytes; }
    int*   offsE  = (int*)w;    w += offsE_bytes;
    int*   offsO  = (int*)w;    w += offsO_bytes;
    int*   gcnt4  = (int*)w;    w += 4 * NBMAX * sizeof(int);
    int*   boffs4 = (int*)w;    w += 4 * (NBMAX + 1) * sizeof(int);
    int*   bcur4  = (int*)w;

    hipMemsetAsync(gcnt4, 0, 4 * NBMAX * sizeof(int), stream);
    // dirs: 0 = a by row, 1 = a by col, 2 = ia by row, 3 = ia by col
    hist_all<<<1024, 256, 0, stream>>>(a_rows, a_cols, ia_rows, ia_cols,
                                       gcnt4, nnz, rsh_s, rsh_p);
    scan_all<<<4, 256, 0, stream>>>(gcnt4, boffs4, bcur4, nb_s, nb_p, nnz,
                                    offsE, offsO, NS, NP8);

    if (fused) {
        const int ntiles2 = (nnz + FTILE - 1) / FTILE;
        struct Mat { const int* r; const int* c; const float* v;
                     float* oe; float* oo; int de, dodd; };
        Mat mats[2] = {
            { a_rows,  a_cols,  a_vals,  out_sc,  out_pc,  0, 1 },
            { ia_rows, ia_cols, ia_vals, out_sic, out_pic, 2, 3 },
        };
        for (int m = 0; m < 2; ++m) {
            const Mat& M = mats[m];
            // one pass over (rows,cols,vals): even buckets -> e1, odd -> e3
            staged_scatter2<<<ntiles2, 256, 0, stream>>>(M.r, M.c, M.v,
                    bcur4 + M.de * NBMAX, bcur4 + M.dodd * NBMAX,
                    edges1, edges3, nnz, rsh_s, rsh_p);
            row_sort1<<<nb_s, 512, 0, stream>>>(edges1, edges2,
                    boffs4 + M.de * (NBMAX + 1), offsE, 0, nb_s, rsh_s, NS, mult8);
            row_gather<<<(NS + 7) / 8, 256, 0, stream>>>(offsE, edges2, p_emb, M.oe, NS);
            row_sort1<<<nb_p, 512, 0, stream>>>(edges3, edges1,
                    boffs4 + M.dodd * (NBMAX + 1), offsO, 1, nb_p, rsh_p, NP, mult8);
            xcd_gather<<<8 * ((NP + 7) / 8), 256, 0, stream>>>(offsO, edges1,
                    s_emb, (float*)edges3, NP);
            reduce8<<<(NP * 64 / 4 + 255) / 256, 256, 0, stream>>>((float*)edges3,
                    M.oo, NP * 64 / 4);
        }
        return;
    }

    // ---- non-fused (ws-tight) path: r8 structure ----
    float* partial = (float*)edges1;
    const int ntiles = (nnz + TILE - 1) / TILE;
    struct Dir { const int* key; const int* other; const float* vals;
                 float* out; int odd; };
    Dir dirs[4] = {
        { a_rows,  a_cols,  a_vals,  out_sc,  0 },
        { a_cols,  a_rows,  a_vals,  out_pc,  1 },
        { ia_rows, ia_cols, ia_vals, out_sic, 0 },
        { ia_cols, ia_rows, ia_vals, out_pic, 1 },
    };
    for (int t = 0; t < 4; ++t) {
        const Dir& D = dirs[t];
        if (!D.odd) {
            staged_scatter<<<ntiles, 256, 0, stream>>>(D.key, D.other, D.vals,
                                                       bcur4 + t * NBMAX, edges1, nnz, rsh_s);
            row_sort1<<<nb_s, 512, 0, stream>>>(edges1, edges2,
                                                boffs4 + t * (NBMAX + 1), offsE,
                                                0, nb_s, rsh_s, NS, mult8);
            row_gather<<<(NS + 7) / 8, 256, 0, stream>>>(offsE, edges2, p_emb, D.out, NS);
        } else {
            staged_scatter<<<ntiles, 256, 0, stream>>>(D.key, D.other, D.vals,
                                                       bcur4 + t * NBMAX, edges1, nnz, rsh_p);
            row_sort1<<<nb_p, 512, 0, stream>>>(edges1, edges2,
                                                boffs4 + t * (NBMAX + 1), offsO,
                                                1, nb_p, rsh_p, NP, mult8);
            xcd_gather<<<8 * ((NP + 7) / 8), 256, 0, stream>>>(offsO, edges2,
                                                               s_emb, partial, NP);
            reduce8<<<(NP * 64 / 4 + 255) / 256, 256, 0, stream>>>(partial, D.out, NP * 64 / 4);
        }
    }
}